// Round 15
// baseline (136.999 us; speedup 1.0000x reference)
//
#include <hip/hip_runtime.h>
#include <cstddef>

#define BATCH 64
#define CCH   512
#define RCH   32
#define HW    1024

typedef __attribute__((ext_vector_type(8))) _Float16 half8;
typedef __attribute__((ext_vector_type(4))) _Float16 half4v;
typedef __attribute__((ext_vector_type(4))) float f32x4;

__device__ inline uint pk2h(float a, float b) {      // 2×f32 -> packed fp16
  auto h = __builtin_amdgcn_cvt_pkrtz(a, b);         // __fp16 ext_vector(2)
  return __builtin_bit_cast(uint, h);
}
__device__ inline ushort h16(float f) {
  _Float16 h = (_Float16)f;
  return __builtin_bit_cast(ushort, h);
}

__device__ inline void gload16(const float* g, float* lds) {
  __builtin_amdgcn_global_load_lds((const __attribute__((address_space(1))) void*)g,
                                   (__attribute__((address_space(3))) void*)lds, 16, 0, 0);
}

// ---------------- K0: weight prep + pos repack -------------------------------
__global__ __launch_bounds__(256) void k_prep(const float* __restrict__ Wred,
    const float* __restrict__ Wrest, const float* __restrict__ Wphi,
    const float* __restrict__ Wth,   const float* __restrict__ Wg,
    const float* __restrict__ Wmask, const float* __restrict__ pos,
    float* __restrict__ Wcomb, _Float16* __restrict__ Whf,
    uint2* __restrict__ posq) {
  const int blk = blockIdx.x;
  const int t = threadIdx.x;
  if (blk >= 256) {
    __shared__ ushort tile[64][68];
    int tb = blk - 256;
    int n0 = (tb >> 4) * 64, m0 = (tb & 15) * 64;
    int nl = t >> 2, c4 = t & 3;
    const float* src = &pos[(size_t)(n0 + nl) * HW + m0 + c4 * 16];
#pragma unroll
    for (int k = 0; k < 4; ++k) {
      float4 p = *(const float4*)(src + k * 4);
      ushort* d = &tile[nl][c4 * 16 + k * 4];
      d[0] = h16(p.x); d[1] = h16(p.y); d[2] = h16(p.z); d[3] = h16(p.w);
    }
    __syncthreads();
    int nl2 = t & 63, mq = t >> 6;
#pragma unroll
    for (int k = 0; k < 4; ++k) {
      int m4l = k * 4 + mq;
      const ushort* s = &tile[nl2][m4l * 4];
      uint2 o;
      o.x = (uint)s[0] | ((uint)s[1] << 16);
      o.y = (uint)s[2] | ((uint)s[3] << 16);
      posq[(size_t)(m0 / 4 + m4l) * HW + n0 + nl2] = o;
    }
    return;
  }
  int tid = blk * 256 + t;
  int job = tid >> 14, idx = tid & 16383;
  if (job == 0) {
    int co = idx >> 5, r = idx & 31;
    float a = 0.f;
#pragma unroll
    for (int rp = 0; rp < RCH; ++rp)
      a += Wrest[co * RCH + rp] * Wmask[rp * RCH + r];
    Wcomb[idx] = a;
  } else {
    const float* Wm = (job == 1) ? Wphi : (job == 2) ? Wth : Wg;
    int rp = idx >> 9, c = idx & 511;
    float a = 0.f;
#pragma unroll
    for (int r = 0; r < RCH; ++r)
      a += Wm[rp * RCH + r] * Wred[r * CCH + c];
    int kk = c >> 5, hl = (c >> 3) & 3, j = c & 7;
    int mix = job - 1, m = rp >> 4, ll = rp & 15;
    size_t off = ((((size_t)kk * 3 + mix) * 2 + m) * 64 + hl * 16 + ll) * 8 + j;
    Whf[off] = (_Float16)a;
  }
}

// ---------------- K1: phi/theta/g = Wc @ x (fp16 MFMA, LDS-staged x) ---------
__global__ __launch_bounds__(256) void k_qkg(const float* __restrict__ x,
    const _Float16* __restrict__ Whf, const float* __restrict__ posdec,
    _Float16* __restrict__ phiT, _Float16* __restrict__ thT,
    _Float16* __restrict__ g) {
  __shared__ float buf[2][32][64];       // 16 KB double-buffered x tile
  __shared__ float gt[4][32][17];        // 8.7 KB g transpose

  const int t = threadIdx.x;
  const int wv = t >> 6, lane = t & 63;
  const int ll = lane & 15, hl = lane >> 4;
  const int b = blockIdx.y;
  const int px0b = blockIdx.x * 64;
  const f32x4 fz = {0.f, 0.f, 0.f, 0.f};

  f32x4 acc[3][2];
#pragma unroll
  for (int m1 = 0; m1 < 3; ++m1)
#pragma unroll
    for (int m2 = 0; m2 < 2; ++m2) acc[m1][m2] = fz;

  {
    const float* xbase = x + ((size_t)b * CCH) * HW + px0b;
#pragma unroll
    for (int rd = 0; rd < 2; ++rd) {
      int ch = rd * 16 + wv * 4 + (lane >> 4);
      gload16(xbase + (size_t)ch * HW + (lane & 15) * 4, &buf[0][rd * 16 + wv * 4][0]);
    }
  }
  __syncthreads();

  for (int kk = 0; kk < 16; ++kk) {
    const int cur = kk & 1;
    if (kk < 15) {
      const float* xbase = x + ((size_t)b * CCH + (kk + 1) * 32) * HW + px0b;
#pragma unroll
      for (int rd = 0; rd < 2; ++rd) {
        int ch = rd * 16 + wv * 4 + (lane >> 4);
        gload16(xbase + (size_t)ch * HW + (lane & 15) * 4, &buf[cur ^ 1][rd * 16 + wv * 4][0]);
      }
    }
    float xv[8];
#pragma unroll
    for (int j = 0; j < 8; ++j) xv[j] = buf[cur][hl * 8 + j][wv * 16 + ll];
    union { half8 h8; uint u[4]; } X;
    X.u[0] = pk2h(xv[0], xv[1]);
    X.u[1] = pk2h(xv[2], xv[3]);
    X.u[2] = pk2h(xv[4], xv[5]);
    X.u[3] = pk2h(xv[6], xv[7]);
#pragma unroll
    for (int mix = 0; mix < 3; ++mix)
#pragma unroll
      for (int m = 0; m < 2; ++m) {
        half8 wh = *(const half8*)&Whf[((((size_t)kk * 3 + mix) * 2 + m) * 64 + lane) * 8];
        acc[mix][m] = __builtin_amdgcn_mfma_f32_16x16x32_f16(wh, X.h8, acc[mix][m], 0, 0, 0);
      }
    __syncthreads();
  }

  // phi/theta: [b][px][32] fp16
#pragma unroll
  for (int mix = 0; mix < 2; ++mix) {
    _Float16* outb = (mix ? thT : phiT) + ((size_t)b * HW + px0b + wv * 16) * 32;
#pragma unroll
    for (int m = 0; m < 2; ++m) {
      f32x4 v = acc[mix][m];
      uint2 o;
      o.x = pk2h(v[0], v[1]);
      o.y = pk2h(v[2], v[3]);
      *(uint2*)(outb + (size_t)ll * 32 + m * 16 + hl * 4) = o;
    }
  }

  // g: [b][r][px] fp16 via LDS transpose, +posdec
  __syncthreads();
#pragma unroll
  for (int m = 0; m < 2; ++m)
#pragma unroll
    for (int i = 0; i < 4; ++i)
      gt[wv][m * 16 + hl * 4 + i][ll] = acc[2][m][i];
  __syncthreads();
#pragma unroll
  for (int rr = 0; rr < 4; ++rr) {
    int r = rr * 8 + hl * 2 + (ll >> 3), p2 = (ll & 7) * 2;
    const float2 pd = *(const float2*)&posdec[(size_t)r * HW + px0b + wv * 16 + p2];
    uint pk = pk2h(gt[wv][r][p2] + pd.x, gt[wv][r][p2 + 1] + pd.y);
    *(uint*)&g[((size_t)b * RCH + r) * HW + px0b + wv * 16 + p2] = pk;
  }
}

// ---------------- K2: flash attention, in-register P repack ------------------
// grid (16, 64), 256 thr = 4 waves; wave owns 16 n rows over ALL 1024 m.
// P -> PV B-frag via DOUBLE ds_bpermute (both mf candidates) + post-select.
__global__ __launch_bounds__(256) void k_attn(const _Float16* __restrict__ phiT,
    const _Float16* __restrict__ thT, const _Float16* __restrict__ g,
    const _Float16* __restrict__ posqh, _Float16* __restrict__ y2h) {
  const int t = threadIdx.x;
  const int wv = t >> 6, lane = t & 63;
  const int ll = lane & 15, hl = lane >> 4;
  const int b = blockIdx.y;
  const int nw = blockIdx.x * 64 + wv * 16;             // wave's 16 n-rows
  const f32x4 fz = {0.f, 0.f, 0.f, 0.f};

  const _Float16* phib = phiT + (size_t)b * (HW * 32);
  const _Float16* thb  = thT  + (size_t)b * (HW * 32);
  const _Float16* gb   = g    + (size_t)b * (RCH * HW);

  // theta B-frag (persistent): col=ll -> n, k=hl*8+j -> channel
  half8 th = *(const half8*)&thb[(size_t)(nw + ll) * 32 + hl * 8];

  // bpermute source-lane byte addresses (source lane = hl_s*16 + ll)
  const int src0 = (((hl & 1) * 2) * 16 + ll) << 2;       // hl_s = (hl&1)*2
  const int src1 = (((hl & 1) * 2 + 1) * 16 + ll) << 2;   // hl_s = (hl&1)*2+1
  const bool hiMf = (hl & 2) != 0;                        // dest needs mf=2ks+1

  f32x4 y[2] = {fz, fz};                 // col=ll -> n, row=hl*4+i -> r
  float m_run = -3e38f, s_run = 0.f;

  for (int ck = 0; ck < 8; ++ck) {
    const int mch = ck * 128;

    // ---- S^T = phi^T @ theta: lane: m = mf*16+hl*4+i, n = ll ----
    f32x4 acc[8];
#pragma unroll
    for (int mf = 0; mf < 8; ++mf) {
      half8 ph = *(const half8*)&phib[(size_t)(mch + mf * 16 + ll) * 32 + hl * 8];
      acc[mf] = __builtin_amdgcn_mfma_f32_16x16x32_f16(ph, th, fz, 0, 0, 0);
    }

    // ---- + pos from posq[m4][n] fp16 (n = ll-consecutive -> coalesced) ----
#pragma unroll
    for (int mf = 0; mf < 8; ++mf) {
      half4v pp = *(const half4v*)&posqh[((size_t)(ck * 32 + mf * 4 + hl) * HW + nw + ll) * 4];
#pragma unroll
      for (int i = 0; i < 4; ++i) acc[mf][i] += (float)pp[i];
    }

    // ---- online softmax over 128-m chunk (row n = ll, reduce over hl) ----
    float mv = acc[0][0];
#pragma unroll
    for (int mf = 0; mf < 8; ++mf)
#pragma unroll
      for (int i = 0; i < 4; ++i) mv = fmaxf(mv, acc[mf][i]);
    mv = fmaxf(mv, __shfl_xor(mv, 16));
    mv = fmaxf(mv, __shfl_xor(mv, 32));
    float mnew = fmaxf(m_run, mv);
    float fac = __expf(m_run - mnew);
    m_run = mnew;
    float s_ = 0.f;
#pragma unroll
    for (int mf = 0; mf < 8; ++mf)
#pragma unroll
      for (int i = 0; i < 4; ++i) {
        float p = __expf(acc[mf][i] - mnew);
        acc[mf][i] = p;
        s_ += p;
      }
    s_ += __shfl_xor(s_, 16);
    s_ += __shfl_xor(s_, 32);
    s_run = s_run * fac + s_;
    y[0] *= fac;
    y[1] *= fac;

    // ---- pack P to fp16 pairs: pu[mf][0]=(i0,i1), pu[mf][1]=(i2,i3) ----
    uint pu[8][2];
#pragma unroll
    for (int mf = 0; mf < 8; ++mf) {
      pu[mf][0] = pk2h(acc[mf][0], acc[mf][1]);
      pu[mf][1] = pk2h(acc[mf][2], acc[mf][3]);
    }

    // ---- PV: B-frag via double ds_bpermute + dest-side select ----
    // dest lane (hl,ll) needs P[n=ll][m=ks*32+hl*8+j]:
    //   j<4  from src lane hl_s=(hl&1)*2,   reg pu[2ks+(hl>>1)][j>>1... word j/2]
    //   j>=4 from src lane hl_s=(hl&1)*2+1, same regs
    // bpermute delivers the SOURCE lane's value -> pull both mf candidates,
    // then select by dest's (hl>>1).
#pragma unroll
    for (int ks = 0; ks < 4; ++ks) {
      uint lo00 = __builtin_amdgcn_ds_bpermute(src0, pu[2 * ks][0]);
      uint lo01 = __builtin_amdgcn_ds_bpermute(src0, pu[2 * ks][1]);
      uint lo10 = __builtin_amdgcn_ds_bpermute(src1, pu[2 * ks][0]);
      uint lo11 = __builtin_amdgcn_ds_bpermute(src1, pu[2 * ks][1]);
      uint hi00 = __builtin_amdgcn_ds_bpermute(src0, pu[2 * ks + 1][0]);
      uint hi01 = __builtin_amdgcn_ds_bpermute(src0, pu[2 * ks + 1][1]);
      uint hi10 = __builtin_amdgcn_ds_bpermute(src1, pu[2 * ks + 1][0]);
      uint hi11 = __builtin_amdgcn_ds_bpermute(src1, pu[2 * ks + 1][1]);
      union { uint u[4]; half8 h8; } B;
      B.u[0] = hiMf ? hi00 : lo00;
      B.u[1] = hiMf ? hi01 : lo01;
      B.u[2] = hiMf ? hi10 : lo10;
      B.u[3] = hiMf ? hi11 : lo11;
#pragma unroll
      for (int rf = 0; rf < 2; ++rf) {
        half8 ag = *(const half8*)&gb[(size_t)(rf * 16 + ll) * HW + mch + ks * 32 + hl * 8];
        y[rf] = __builtin_amdgcn_mfma_f32_16x16x32_f16(ag, B.h8, y[rf], 0, 0, 0);
      }
    }
  }

  // ---- normalize + store fp16 n-major: y2h[b][n][r], lane owns r=hl*4..+3 ----
  float inv = 1.f / s_run;
#pragma unroll
  for (int rf = 0; rf < 2; ++rf) {
    uint2 o;
    o.x = pk2h(y[rf][0] * inv, y[rf][1] * inv);
    o.y = pk2h(y[rf][2] * inv, y[rf][3] * inv);
    *(uint2*)&y2h[((size_t)b * HW + nw + ll) * RCH + rf * 16 + hl * 4] = o;
  }
}

// ---------------- K3: out = x + Wcomb @ y --------------------------------
__global__ __launch_bounds__(256) void k_restore(const float* __restrict__ x,
    const float* __restrict__ Wcomb, const _Float16* __restrict__ y2h,
    float* __restrict__ out) {
  const int t = threadIdx.x;
  const int gp = blockIdx.y * 256 + t;
  const int b = gp >> 10, n = gp & 1023;
  const int co0 = blockIdx.x * 32;

  // y row: 32 fp16 = 64 B contiguous per thread (FOUR uint4 loads)
  float yv[RCH];
  {
    union { uint4 u4[4]; _Float16 h[RCH]; } Y;
    const uint4* yp = (const uint4*)&y2h[((size_t)b * HW + n) * RCH];
    Y.u4[0] = yp[0];
    Y.u4[1] = yp[1];
    Y.u4[2] = yp[2];
    Y.u4[3] = yp[3];
#pragma unroll
    for (int r = 0; r < RCH; ++r) yv[r] = (float)Y.h[r];
  }

  const float* xb = x + ((size_t)b * CCH) * HW + n;
  float* ob = out + ((size_t)b * CCH) * HW + n;
  for (int co = co0; co < co0 + 32; ++co) {
    float a = xb[(size_t)co * HW];
#pragma unroll
    for (int qq = 0; qq < RCH; qq += 4) {
      const float4 w = *(const float4*)(Wcomb + co * RCH + qq);  // uniform -> s_load
      a += w.x * yv[qq] + w.y * yv[qq + 1] + w.z * yv[qq + 2] + w.w * yv[qq + 3];
    }
    ob[(size_t)co * HW] = a;
  }
}

extern "C" void kernel_launch(void* const* d_in, const int* in_sizes, int n_in,
                              void* d_out, int out_size, void* d_ws, size_t ws_size,
                              hipStream_t stream) {
  const float* x      = (const float*)d_in[0];
  const float* Wred   = (const float*)d_in[1];
  const float* Wrest  = (const float*)d_in[2];
  const float* Wphi   = (const float*)d_in[3];
  const float* Wth    = (const float*)d_in[4];
  const float* Wg     = (const float*)d_in[5];
  const float* Wmask  = (const float*)d_in[6];
  const float* pos    = (const float*)d_in[7];
  const float* posdec = (const float*)d_in[8];
  float* out = (float*)d_out;

  const size_t NE = (size_t)BATCH * RCH * HW;      // 2M elements
  _Float16* phiT = (_Float16*)d_ws;                // 4 MB
  _Float16* thT  = phiT + NE;                      // 4 MB
  _Float16* gbuf = thT + NE;                       // 4 MB
  _Float16* y2h  = gbuf + NE;                      // 4 MB (fp16, n-major)
  float*    Wcomb = (float*)(y2h + NE);            // 64 KB
  _Float16* Whf  = (_Float16*)(Wcomb + CCH * RCH); // 96 KB
  _Float16* posqh = Whf + 3 * RCH * CCH;           // 2 MB, 16B-aligned

  k_prep   <<<dim3(512),     dim3(256), 0, stream>>>(Wred, Wrest, Wphi, Wth, Wg, Wmask,
                                                     pos, Wcomb, Whf, (uint2*)posqh);
  k_qkg    <<<dim3(16, 64),  dim3(256), 0, stream>>>(x, Whf, posdec, phiT, thT, gbuf);
  k_attn   <<<dim3(16, 64),  dim3(256), 0, stream>>>(phiT, thT, gbuf, posqh, y2h);
  k_restore<<<dim3(16, 256), dim3(256), 0, stream>>>(x, Wcomb, y2h, out);
}

// Round 16
// 133.643 us; speedup vs baseline: 1.0251x; 1.0251x over previous
//
#include <hip/hip_runtime.h>
#include <cstddef>

#define BATCH 64
#define CCH   512
#define RCH   32
#define HW    1024

typedef __attribute__((ext_vector_type(8))) _Float16 half8;
typedef __attribute__((ext_vector_type(4))) _Float16 half4v;
typedef __attribute__((ext_vector_type(4))) float f32x4;

__device__ inline uint pk2h(float a, float b) {      // 2×f32 -> packed fp16
  auto h = __builtin_amdgcn_cvt_pkrtz(a, b);         // __fp16 ext_vector(2)
  return __builtin_bit_cast(uint, h);
}
__device__ inline ushort h16(float f) {
  _Float16 h = (_Float16)f;
  return __builtin_bit_cast(ushort, h);
}

__device__ inline void gload16(const float* g, float* lds) {
  __builtin_amdgcn_global_load_lds((const __attribute__((address_space(1))) void*)g,
                                   (__attribute__((address_space(3))) void*)lds, 16, 0, 0);
}

// ---------------- K0: weight prep + pos repack -------------------------------
// blk<256: job0 Wcomb = Wrest@Wmask (fp32); job1..3 Wc[mix]=Wmix@Wred -> fp16,
//          packed in MFMA-frag order: [kk][mix][m][lane][8]
// blk 256..511: pos fp32 [n][m] -> posq fp16 [m4][n] (uint2 = 4 consecutive m)
__global__ __launch_bounds__(256) void k_prep(const float* __restrict__ Wred,
    const float* __restrict__ Wrest, const float* __restrict__ Wphi,
    const float* __restrict__ Wth,   const float* __restrict__ Wg,
    const float* __restrict__ Wmask, const float* __restrict__ pos,
    float* __restrict__ Wcomb, _Float16* __restrict__ Whf,
    uint2* __restrict__ posq) {
  const int blk = blockIdx.x;
  const int t = threadIdx.x;
  if (blk >= 256) {
    __shared__ ushort tile[64][68];
    int tb = blk - 256;
    int n0 = (tb >> 4) * 64, m0 = (tb & 15) * 64;
    int nl = t >> 2, c4 = t & 3;
    const float* src = &pos[(size_t)(n0 + nl) * HW + m0 + c4 * 16];
#pragma unroll
    for (int k = 0; k < 4; ++k) {
      float4 p = *(const float4*)(src + k * 4);
      ushort* d = &tile[nl][c4 * 16 + k * 4];
      d[0] = h16(p.x); d[1] = h16(p.y); d[2] = h16(p.z); d[3] = h16(p.w);
    }
    __syncthreads();
    int nl2 = t & 63, mq = t >> 6;
#pragma unroll
    for (int k = 0; k < 4; ++k) {
      int m4l = k * 4 + mq;
      const ushort* s = &tile[nl2][m4l * 4];
      uint2 o;
      o.x = (uint)s[0] | ((uint)s[1] << 16);
      o.y = (uint)s[2] | ((uint)s[3] << 16);
      posq[(size_t)(m0 / 4 + m4l) * HW + n0 + nl2] = o;
    }
    return;
  }
  int tid = blk * 256 + t;
  int job = tid >> 14, idx = tid & 16383;
  if (job == 0) {
    int co = idx >> 5, r = idx & 31;
    float a = 0.f;
#pragma unroll
    for (int rp = 0; rp < RCH; ++rp)
      a += Wrest[co * RCH + rp] * Wmask[rp * RCH + r];
    Wcomb[idx] = a;
  } else {
    const float* Wm = (job == 1) ? Wphi : (job == 2) ? Wth : Wg;
    int rp = idx >> 9, c = idx & 511;
    float a = 0.f;
#pragma unroll
    for (int r = 0; r < RCH; ++r)
      a += Wm[rp * RCH + r] * Wred[r * CCH + c];
    // frag-order pack: kk=c>>5, hl=(c>>3)&3, j=c&7; mix=job-1, m=rp>>4, ll=rp&15
    int kk = c >> 5, hl = (c >> 3) & 3, j = c & 7;
    int mix = job - 1, m = rp >> 4, ll = rp & 15;
    size_t off = ((((size_t)kk * 3 + mix) * 2 + m) * 64 + hl * 16 + ll) * 8 + j;
    Whf[off] = (_Float16)a;
  }
}

// ---------------- K1: phi/theta/g = Wc @ x (fp16 MFMA, LDS-staged x) ---------
// grid (16, 64), 256 thr = 4 waves, 16 px per wave, 64 px per block
__global__ __launch_bounds__(256) void k_qkg(const float* __restrict__ x,
    const _Float16* __restrict__ Whf, const float* __restrict__ posdec,
    _Float16* __restrict__ phiT, _Float16* __restrict__ thT,
    _Float16* __restrict__ g) {
  __shared__ float buf[2][32][64];       // 16 KB double-buffered x tile
  __shared__ float gt[4][32][17];        // 8.7 KB g transpose

  const int t = threadIdx.x;
  const int wv = t >> 6, lane = t & 63;
  const int ll = lane & 15, hl = lane >> 4;
  const int b = blockIdx.y;
  const int px0b = blockIdx.x * 64;
  const f32x4 fz = {0.f, 0.f, 0.f, 0.f};

  f32x4 acc[3][2];
#pragma unroll
  for (int m1 = 0; m1 < 3; ++m1)
#pragma unroll
    for (int m2 = 0; m2 < 2; ++m2) acc[m1][m2] = fz;

  // stage kk=0: 2 rounds x (4 waves x 64 lanes x 16B) = 8 KB
  {
    const float* xbase = x + ((size_t)b * CCH) * HW + px0b;
#pragma unroll
    for (int rd = 0; rd < 2; ++rd) {
      int ch = rd * 16 + wv * 4 + (lane >> 4);
      gload16(xbase + (size_t)ch * HW + (lane & 15) * 4, &buf[0][rd * 16 + wv * 4][0]);
    }
  }
  __syncthreads();

  for (int kk = 0; kk < 16; ++kk) {
    const int cur = kk & 1;
    if (kk < 15) {
      const float* xbase = x + ((size_t)b * CCH + (kk + 1) * 32) * HW + px0b;
#pragma unroll
      for (int rd = 0; rd < 2; ++rd) {
        int ch = rd * 16 + wv * 4 + (lane >> 4);
        gload16(xbase + (size_t)ch * HW + (lane & 15) * 4, &buf[cur ^ 1][rd * 16 + wv * 4][0]);
      }
    }
    float xv[8];
#pragma unroll
    for (int j = 0; j < 8; ++j) xv[j] = buf[cur][hl * 8 + j][wv * 16 + ll];
    union { half8 h8; uint u[4]; } X;
    X.u[0] = pk2h(xv[0], xv[1]);
    X.u[1] = pk2h(xv[2], xv[3]);
    X.u[2] = pk2h(xv[4], xv[5]);
    X.u[3] = pk2h(xv[6], xv[7]);
#pragma unroll
    for (int mix = 0; mix < 3; ++mix)
#pragma unroll
      for (int m = 0; m < 2; ++m) {
        half8 wh = *(const half8*)&Whf[((((size_t)kk * 3 + mix) * 2 + m) * 64 + lane) * 8];
        acc[mix][m] = __builtin_amdgcn_mfma_f32_16x16x32_f16(wh, X.h8, acc[mix][m], 0, 0, 0);
      }
    __syncthreads();
  }

  // phi/theta: [b][px][32] fp16
#pragma unroll
  for (int mix = 0; mix < 2; ++mix) {
    _Float16* outb = (mix ? thT : phiT) + ((size_t)b * HW + px0b + wv * 16) * 32;
#pragma unroll
    for (int m = 0; m < 2; ++m) {
      f32x4 v = acc[mix][m];
      uint2 o;
      o.x = pk2h(v[0], v[1]);
      o.y = pk2h(v[2], v[3]);
      *(uint2*)(outb + (size_t)ll * 32 + m * 16 + hl * 4) = o;
    }
  }

  // g: [b][r][px] fp16 via LDS transpose, +posdec
  __syncthreads();
#pragma unroll
  for (int m = 0; m < 2; ++m)
#pragma unroll
    for (int i = 0; i < 4; ++i)
      gt[wv][m * 16 + hl * 4 + i][ll] = acc[2][m][i];
  __syncthreads();
#pragma unroll
  for (int rr = 0; rr < 4; ++rr) {
    int r = rr * 8 + hl * 2 + (ll >> 3), p2 = (ll & 7) * 2;
    const float2 pd = *(const float2*)&posdec[(size_t)r * HW + px0b + wv * 16 + p2];
    uint pk = pk2h(gt[wv][r][p2] + pd.x, gt[wv][r][p2 + 1] + pd.y);
    *(uint*)&g[((size_t)b * RCH + r) * HW + px0b + wv * 16 + p2] = pk;
  }
}

// ---------------- K2: flash attention, fp16, per-wave-complete ---------------
// grid (8, 64), 512 thr = 8 waves; wave owns 16 n rows over ALL 1024 m.
// Output y2h fp16, n-major: [b][n][32]
__global__ __launch_bounds__(512) void k_attn(const _Float16* __restrict__ phiT,
    const _Float16* __restrict__ thT, const _Float16* __restrict__ g,
    const _Float16* __restrict__ posqh, _Float16* __restrict__ y2h) {
  __shared__ __align__(16) _Float16 slabm[8][16][72];   // 18.4 KB P slabs

  const int t = threadIdx.x;
  const int wv = t >> 6, lane = t & 63;
  const int ll = lane & 15, hl = lane >> 4;
  const int b = blockIdx.y;
  const int nw = blockIdx.x * 128 + wv * 16;            // wave's 16 n-rows
  const f32x4 fz = {0.f, 0.f, 0.f, 0.f};

  const _Float16* phib = phiT + (size_t)b * (HW * 32);
  const _Float16* thb  = thT  + (size_t)b * (HW * 32);
  const _Float16* gb   = g    + (size_t)b * (RCH * HW);

  // theta B-frag (persistent): col=ll -> n, k=hl*8+j -> channel
  half8 th = *(const half8*)&thb[(size_t)(nw + ll) * 32 + hl * 8];

  f32x4 y[2] = {fz, fz};                 // col=ll -> n, row=hl*4+i -> r
  float m_run = -3e38f, s_run = 0.f;

  for (int ck = 0; ck < 8; ++ck) {
    const int mch = ck * 128;

    // ---- S^T = phi^T @ theta: lane: m = mf*16+hl*4+i, n = ll ----
    f32x4 acc[8];
#pragma unroll
    for (int mf = 0; mf < 8; ++mf) {
      half8 ph = *(const half8*)&phib[(size_t)(mch + mf * 16 + ll) * 32 + hl * 8];
      acc[mf] = __builtin_amdgcn_mfma_f32_16x16x32_f16(ph, th, fz, 0, 0, 0);
    }

    // ---- + pos from posq[m4][n] fp16 (n = ll-consecutive -> coalesced) ----
#pragma unroll
    for (int mf = 0; mf < 8; ++mf) {
      half4v pp = *(const half4v*)&posqh[((size_t)(ck * 32 + mf * 4 + hl) * HW + nw + ll) * 4];
#pragma unroll
      for (int i = 0; i < 4; ++i) acc[mf][i] += (float)pp[i];
    }

    // ---- online softmax over 128-m chunk (row n = ll, reduce over hl) ----
    float mv = acc[0][0];
#pragma unroll
    for (int mf = 0; mf < 8; ++mf)
#pragma unroll
      for (int i = 0; i < 4; ++i) mv = fmaxf(mv, acc[mf][i]);
    mv = fmaxf(mv, __shfl_xor(mv, 16));
    mv = fmaxf(mv, __shfl_xor(mv, 32));
    float mnew = fmaxf(m_run, mv);
    float fac = __expf(m_run - mnew);
    m_run = mnew;
    float s_ = 0.f;
#pragma unroll
    for (int mf = 0; mf < 8; ++mf)
#pragma unroll
      for (int i = 0; i < 4; ++i) {
        float p = __expf(acc[mf][i] - mnew);
        acc[mf][i] = p;
        s_ += p;
      }
    s_ += __shfl_xor(s_, 16);
    s_ += __shfl_xor(s_, 32);
    s_run = s_run * fac + s_;
    y[0] *= fac;
    y[1] *= fac;

    // ---- PV in two 64-m halves through per-wave slab ----
#pragma unroll
    for (int h = 0; h < 2; ++h) {
#pragma unroll
      for (int mf2 = 0; mf2 < 4; ++mf2) {
        f32x4 v = acc[h * 4 + mf2];
        uint2 w;
        w.x = pk2h(v[0], v[1]);
        w.y = pk2h(v[2], v[3]);
        *(uint2*)&slabm[wv][ll][mf2 * 16 + hl * 4] = w;
      }
      asm volatile("s_waitcnt lgkmcnt(0)" ::: "memory");
      __builtin_amdgcn_sched_barrier(0);
#pragma unroll
      for (int ks = 0; ks < 2; ++ks) {
        half8 bfr = *(const half8*)&slabm[wv][ll][ks * 32 + hl * 8];
#pragma unroll
        for (int rf = 0; rf < 2; ++rf) {
          half8 ag = *(const half8*)&gb[(size_t)(rf * 16 + ll) * HW + mch + h * 64 + ks * 32 + hl * 8];
          y[rf] = __builtin_amdgcn_mfma_f32_16x16x32_f16(ag, bfr, y[rf], 0, 0, 0);
        }
      }
      asm volatile("s_waitcnt lgkmcnt(0)" ::: "memory");
      __builtin_amdgcn_sched_barrier(0);
    }
  }

  // ---- normalize + store fp16 n-major: y2h[b][n][r], lane owns r=hl*4..+3 ----
  float inv = 1.f / s_run;
#pragma unroll
  for (int rf = 0; rf < 2; ++rf) {
    uint2 o;
    o.x = pk2h(y[rf][0] * inv, y[rf][1] * inv);
    o.y = pk2h(y[rf][2] * inv, y[rf][3] * inv);
    *(uint2*)&y2h[((size_t)b * HW + nw + ll) * RCH + rf * 16 + hl * 4] = o;
  }
}

// ---------------- K3: out = x + Wcomb @ y --------------------------------
// grid (16 co-groups, 256 px-groups): blocks sharing y2h rows are consecutive
// in dispatch order -> same-XCD L2 hits; 32 co per block for latency hiding.
__global__ __launch_bounds__(256) void k_restore(const float* __restrict__ x,
    const float* __restrict__ Wcomb, const _Float16* __restrict__ y2h,
    float* __restrict__ out) {
  const int t = threadIdx.x;
  const int gp = blockIdx.y * 256 + t;
  const int b = gp >> 10, n = gp & 1023;
  const int co0 = blockIdx.x * 32;

  // y row: 32 fp16 = 64 B contiguous per thread (FOUR uint4 loads)
  float yv[RCH];
  {
    union { uint4 u4[4]; _Float16 h[RCH]; } Y;
    const uint4* yp = (const uint4*)&y2h[((size_t)b * HW + n) * RCH];
    Y.u4[0] = yp[0];
    Y.u4[1] = yp[1];
    Y.u4[2] = yp[2];
    Y.u4[3] = yp[3];
#pragma unroll
    for (int r = 0; r < RCH; ++r) yv[r] = (float)Y.h[r];
  }

  const float* xb = x + ((size_t)b * CCH) * HW + n;
  float* ob = out + ((size_t)b * CCH) * HW + n;
  for (int co = co0; co < co0 + 32; ++co) {
    float a = xb[(size_t)co * HW];
#pragma unroll
    for (int qq = 0; qq < RCH; qq += 4) {
      const float4 w = *(const float4*)(Wcomb + co * RCH + qq);  // uniform -> s_load
      a += w.x * yv[qq] + w.y * yv[qq + 1] + w.z * yv[qq + 2] + w.w * yv[qq + 3];
    }
    ob[(size_t)co * HW] = a;
  }
}

extern "C" void kernel_launch(void* const* d_in, const int* in_sizes, int n_in,
                              void* d_out, int out_size, void* d_ws, size_t ws_size,
                              hipStream_t stream) {
  const float* x      = (const float*)d_in[0];
  const float* Wred   = (const float*)d_in[1];
  const float* Wrest  = (const float*)d_in[2];
  const float* Wphi   = (const float*)d_in[3];
  const float* Wth    = (const float*)d_in[4];
  const float* Wg     = (const float*)d_in[5];
  const float* Wmask  = (const float*)d_in[6];
  const float* pos    = (const float*)d_in[7];
  const float* posdec = (const float*)d_in[8];
  float* out = (float*)d_out;

  const size_t NE = (size_t)BATCH * RCH * HW;      // 2M elements
  _Float16* phiT = (_Float16*)d_ws;                // 4 MB
  _Float16* thT  = phiT + NE;                      // 4 MB
  _Float16* gbuf = thT + NE;                       // 4 MB
  _Float16* y2h  = gbuf + NE;                      // 4 MB (fp16, n-major)
  float*    Wcomb = (float*)(y2h + NE);            // 64 KB
  _Float16* Whf  = (_Float16*)(Wcomb + CCH * RCH); // 96 KB
  _Float16* posqh = Whf + 3 * RCH * CCH;           // 2 MB, 16B-aligned

  k_prep   <<<dim3(512),     dim3(256), 0, stream>>>(Wred, Wrest, Wphi, Wth, Wg, Wmask,
                                                     pos, Wcomb, Whf, (uint2*)posqh);
  k_qkg    <<<dim3(16, 64),  dim3(256), 0, stream>>>(x, Whf, posdec, phiT, thT, gbuf);
  k_attn   <<<dim3(8, 64),   dim3(512), 0, stream>>>(phiT, thT, gbuf, posqh, y2h);
  k_restore<<<dim3(16, 256), dim3(256), 0, stream>>>(x, Wcomb, y2h, out);
}